// Round 9
// baseline (9875.333 us; speedup 1.0000x reference)
//
#include <hip/hip_runtime.h>
#include <math.h>

// B=16, N=8192, L=512, D=384, FF=1536.
// INPUTS fp32, OUTPUT fp32 (verified R5-R8: bf16 reads of inputs NaN; bf16
// writes to d_out produce the deterministic 6.75 position-scramble error).
// Intermediates bf16 (+fp32 attention partials). Per-batch pipeline.
// Workspace (bytes, peak ~38.2 MB):
//   hA 0 (6291456)  hB 6291456  KVb 12582912 (12582912)
//   num 25165824 (fp32 [8][512][384])  den 31457280 (fp32 [8][512])
//   qn 31473664  qb 31866880  aob 32260096  x1b 32653312  f0b 33046528
//   f1b 33439744 (3145728)  glb 36585472 (1572864)  end 38158336

typedef unsigned short u16;
typedef unsigned int   u32;

__device__ __forceinline__ float b2f(u16 v) {
    return __uint_as_float(((u32)v) << 16);
}
__device__ __forceinline__ u16 f2b(float f) {
    u32 u = __float_as_uint(f);
    return (u16)((u + 0x7FFFu + ((u >> 16) & 1u)) >> 16);   // RNE
}
__device__ __forceinline__ float4 ldb4(const u16* p) {   // 4 bf16 -> float4
    uint2 v = *(const uint2*)p;
    float4 f;
    f.x = __uint_as_float(v.x << 16);
    f.y = __uint_as_float(v.x & 0xFFFF0000u);
    f.z = __uint_as_float(v.y << 16);
    f.w = __uint_as_float(v.y & 0xFFFF0000u);
    return f;
}
__device__ __forceinline__ void stb4(u16* p, float4 f) {
    uint2 v;
    v.x = (u32)f2b(f.x) | ((u32)f2b(f.y) << 16);
    v.y = (u32)f2b(f.z) | ((u32)f2b(f.w) << 16);
    *(uint2*)p = v;
}

// ---------------------------------------------------------------------------
// Layer 0: h = relu(x @ w0 + b0); x fp32 [8192][3] (one batch), out bf16
__global__ __launch_bounds__(256) void layer0_kernel(
    const float* __restrict__ X, const float* __restrict__ W0,
    const float* __restrict__ B0, u16* __restrict__ H, int total4)
{
    int idx = blockIdx.x * 256 + threadIdx.x;
    if (idx >= total4) return;
    int e = idx * 4;
    int m = e / 384;
    int j = e - m * 384;
    float x0 = X[m * 3 + 0], x1 = X[m * 3 + 1], x2 = X[m * 3 + 2];
    float4 w0 = *(const float4*)(W0 + j);
    float4 w1 = *(const float4*)(W0 + 384 + j);
    float4 w2 = *(const float4*)(W0 + 768 + j);
    float4 bb = *(const float4*)(B0 + j);
    float4 v;
    v.x = fmaxf(bb.x + x0 * w0.x + x1 * w1.x + x2 * w2.x, 0.f);
    v.y = fmaxf(bb.y + x0 * w0.y + x1 * w1.y + x2 * w2.y, 0.f);
    v.z = fmaxf(bb.z + x0 * w0.z + x1 * w1.z + x2 * w2.z, 0.f);
    v.w = fmaxf(bb.w + x0 * w0.w + x1 * w1.w + x2 * w2.w, 0.f);
    stb4(H + e, v);
}

// ---------------------------------------------------------------------------
// LayerNorm; input fp32 (IN_F32=1) or bf16; g,b fp32; out bf16. 4 rows/block.
template<int IN_F32>
__global__ __launch_bounds__(256) void ln_kernel(
    const void* __restrict__ Xv, const float* __restrict__ g,
    const float* __restrict__ b, u16* __restrict__ Y, int rows)
{
    int w = threadIdx.x >> 6, lane = threadIdx.x & 63;
    int row = blockIdx.x * 4 + w;
    if (row >= rows) return;
    float v[6];
    float s = 0.f, ss = 0.f;
#pragma unroll
    for (int i = 0; i < 6; ++i) {
        int c = i * 64 + lane;
        v[i] = IN_F32 ? ((const float*)Xv)[(long long)row * 384 + c]
                      : b2f(((const u16*)Xv)[(long long)row * 384 + c]);
        s += v[i]; ss += v[i] * v[i];
    }
#pragma unroll
    for (int m = 32; m; m >>= 1) {
        s  += __shfl_xor(s, m, 64);
        ss += __shfl_xor(ss, m, 64);
    }
    float mean = s * (1.0f / 384.0f);
    float var  = ss * (1.0f / 384.0f) - mean * mean;
    float rs = rsqrtf(fmaxf(var, 0.f) + 1e-5f);
    u16* yr = Y + (long long)row * 384;
#pragma unroll
    for (int i = 0; i < 6; ++i) {
        int c = i * 64 + lane;
        yr[c] = f2b((v[i] - mean) * rs * g[c] + b[c]);
    }
}

// ---------------------------------------------------------------------------
// GEMM: C = A@B + bias (+res) [+relu]. A bf16, B fp32, bias fp32.
// RES_F32: residual dtype. OUT_F32: C dtype (fp32 for final output).
// 64x64 tile. M%64==0, N%64==0, K%16==0.
template<int RES_F32, int OUT_F32>
__global__ __launch_bounds__(256) void gemm_kernel(
    const u16* __restrict__ A, const float* __restrict__ B,
    const float* __restrict__ bias, const void* __restrict__ res,
    void* __restrict__ C,
    int M, int N, int K,
    int lda, int ldb, int ldc, int ldres, int relu)
{
    __shared__ float As[16][68];
    __shared__ float Bs[16][68];
    const int tid = threadIdx.x;
    const int tx = tid & 15, ty = tid >> 4;
    const int m0 = blockIdx.x * 64;
    const int n0 = blockIdx.y * 64;
    float acc[4][4] = {};
    const int ar = tid >> 2;
    const int ac = (tid & 3) * 4;
    for (int k0 = 0; k0 < K; k0 += 16) {
        __syncthreads();
        {
            float4 av = ldb4(A + (long long)(m0 + ar) * lda + (k0 + ac));
            As[ac + 0][ar] = av.x;
            As[ac + 1][ar] = av.y;
            As[ac + 2][ar] = av.z;
            As[ac + 3][ar] = av.w;
        }
        {
            const int br = tid >> 4;
            const int bc = (tid & 15) * 4;
            float4 bv = *(const float4*)(B + (long long)(k0 + br) * ldb + (n0 + bc));
            *(float4*)&Bs[br][bc] = bv;
        }
        __syncthreads();
#pragma unroll
        for (int kk = 0; kk < 16; ++kk) {
            float4 a4 = *(const float4*)&As[kk][ty * 4];
            float4 b4 = *(const float4*)&Bs[kk][tx * 4];
            float a[4] = {a4.x, a4.y, a4.z, a4.w};
            float b[4] = {b4.x, b4.y, b4.z, b4.w};
#pragma unroll
            for (int i = 0; i < 4; ++i)
#pragma unroll
                for (int j = 0; j < 4; ++j)
                    acc[i][j] = fmaf(a[i], b[j], acc[i][j]);
        }
    }
    float4 bv4 = make_float4(0.f, 0.f, 0.f, 0.f);
    if (bias) bv4 = *(const float4*)(bias + n0 + tx * 4);
#pragma unroll
    for (int i = 0; i < 4; ++i) {
        const int m = m0 + ty * 4 + i;
        float4 v;
        v.x = acc[i][0] + bv4.x;
        v.y = acc[i][1] + bv4.y;
        v.z = acc[i][2] + bv4.z;
        v.w = acc[i][3] + bv4.w;
        if (relu) {
            v.x = fmaxf(v.x, 0.f); v.y = fmaxf(v.y, 0.f);
            v.z = fmaxf(v.z, 0.f); v.w = fmaxf(v.w, 0.f);
        }
        if (res) {
            long long ro = (long long)m * ldres + n0 + tx * 4;
            float4 r4;
            if (RES_F32) r4 = *(const float4*)((const float*)res + ro);
            else         r4 = ldb4((const u16*)res + ro);
            v.x += r4.x; v.y += r4.y; v.z += r4.z; v.w += r4.w;
        }
        long long co = (long long)m * ldc + n0 + tx * 4;
        if (OUT_F32) *(float4*)((float*)C + co) = v;
        else         stb4((u16*)C + co, v);
    }
}

// ---------------------------------------------------------------------------
// Attention partials for ONE batch, split over KV chunks.
// Block = (q-tile of 16, chunk of 1024 KV rows). Logits tiny; clamp for safety.
// NUM[chunk][q][d] = sum_n exp(l) V[n][d], DEN[chunk][q] = sum_n exp(l).
__global__ __launch_bounds__(256) void flash_part_kernel(
    const u16* __restrict__ Q,      // [512][384] bf16
    const u16* __restrict__ KV,     // [8192][768] bf16 (K 0..383, V 384..767)
    float* __restrict__ NUM,        // [8][512][384] fp32
    float* __restrict__ DEN)        // [8][512] fp32
{
    __shared__ u16 Qs[16][388];
    __shared__ u16 Ks[32][388];
    __shared__ u16 Vs[32][388];
    __shared__ float Ps[16][36];
    __shared__ float rs[16];
    const int tid = threadIdx.x;
    const int q0 = blockIdx.x * 16;
    const int chunk = blockIdx.y;
#pragma unroll
    for (int s = 0; s < 6; ++s) {
        int slot = tid + s * 256;
        int r = slot / 96, c4 = slot % 96;
        *(ushort4*)&Qs[r][c4 * 4] = *(const ushort4*)(Q + (q0 + r) * 384 + c4 * 4);
    }
    if (tid < 16) rs[tid] = 0.f;
    const int sx = tid & 15, sy = tid >> 4;
    float O[24] = {};
    for (int t = 0; t < 32; ++t) {
        const int n0 = chunk * 1024 + t * 32;
        __syncthreads();
#pragma unroll
        for (int s = 0; s < 12; ++s) {
            int slot = tid + s * 256;
            int r = slot / 96, c4 = slot % 96;
            const u16* src = KV + (long long)(n0 + r) * 768;
            *(ushort4*)&Ks[r][c4 * 4] = *(const ushort4*)(src + c4 * 4);
            *(ushort4*)&Vs[r][c4 * 4] = *(const ushort4*)(src + 384 + c4 * 4);
        }
        __syncthreads();
        float sacc[2] = {};
        for (int k = 0; k < 384; k += 4) {
            float4 a0 = ldb4(&Qs[sy][k]);
#pragma unroll
            for (int j = 0; j < 2; ++j) {
                float4 bv = ldb4(&Ks[sx + 16 * j][k]);
                sacc[j] = fmaf(a0.x, bv.x, sacc[j]);
                sacc[j] = fmaf(a0.y, bv.y, sacc[j]);
                sacc[j] = fmaf(a0.z, bv.z, sacc[j]);
                sacc[j] = fmaf(a0.w, bv.w, sacc[j]);
            }
        }
#pragma unroll
        for (int j = 0; j < 2; ++j) {
            float l = sacc[j] * 0.05103103630798288f;   // 384^-0.5
            l = fminf(fmaxf(l, -60.f), 60.f);
            Ps[sy][sx + 16 * j] = __expf(l);
        }
        __syncthreads();
        if (tid < 16) {
            float s = 0.f;
#pragma unroll
            for (int n4 = 0; n4 < 8; ++n4) {
                float4 p4 = *(const float4*)&Ps[tid][n4 * 4];
                s += p4.x + p4.y + p4.z + p4.w;
            }
            rs[tid] += s;
        }
        for (int n = 0; n < 32; ++n) {
            float p = Ps[sy][n];
            const u16* vr = &Vs[n][sx * 24];
#pragma unroll
            for (int j4 = 0; j4 < 6; ++j4) {
                float4 v4 = ldb4(vr + j4 * 4);
                O[j4 * 4 + 0] = fmaf(p, v4.x, O[j4 * 4 + 0]);
                O[j4 * 4 + 1] = fmaf(p, v4.y, O[j4 * 4 + 1]);
                O[j4 * 4 + 2] = fmaf(p, v4.z, O[j4 * 4 + 2]);
                O[j4 * 4 + 3] = fmaf(p, v4.w, O[j4 * 4 + 3]);
            }
        }
    }
    __syncthreads();
    float* nd = NUM + ((long long)chunk * 512 + q0 + sy) * 384 + sx * 24;
#pragma unroll
    for (int j4 = 0; j4 < 6; ++j4)
        *(float4*)(nd + j4 * 4) =
            make_float4(O[j4 * 4 + 0], O[j4 * 4 + 1], O[j4 * 4 + 2], O[j4 * 4 + 3]);
    if (tid < 16) DEN[chunk * 512 + q0 + tid] = rs[tid];
}

// ---------------------------------------------------------------------------
// AO[q][d] = sum_c NUM[c][q][d] / sum_c DEN[c][q]  -> bf16
__global__ __launch_bounds__(256) void attn_reduce_kernel(
    const float* __restrict__ NUM, const float* __restrict__ DEN,
    u16* __restrict__ AO)           // [512][384] bf16
{
    int idx = blockIdx.x * 256 + threadIdx.x;   // 49152 = 512 * 96
    int q = idx / 96, j = (idx - q * 96) * 4;
    float4 s = make_float4(0.f, 0.f, 0.f, 0.f);
    float d = 0.f;
#pragma unroll
    for (int c = 0; c < 8; ++c) {
        float4 v = *(const float4*)(NUM + ((long long)c * 512 + q) * 384 + j);
        s.x += v.x; s.y += v.y; s.z += v.z; s.w += v.w;
        d += DEN[c * 512 + q];
    }
    float inv = 1.0f / d;
    s.x *= inv; s.y *= inv; s.z *= inv; s.w *= inv;
    stb4(AO + (long long)q * 384 + j, s);
}

// ---------------------------------------------------------------------------
// GEGLU: O[m][j] = F[m][j] * gelu_exact(F[m][1536+j]); F bf16 [512][3072]
__global__ __launch_bounds__(256) void geglu_kernel(
    const u16* __restrict__ F, u16* __restrict__ O, int total4)
{
    int idx = blockIdx.x * 256 + threadIdx.x;
    if (idx >= total4) return;
    int e = idx * 4;
    int m = e / 1536;
    int j = e - m * 1536;
    float4 a = ldb4(F + (long long)m * 3072 + j);
    float4 g = ldb4(F + (long long)m * 3072 + 1536 + j);
    float4 v;
    v.x = a.x * 0.5f * g.x * (1.0f + erff(g.x * 0.70710678118654752f));
    v.y = a.y * 0.5f * g.y * (1.0f + erff(g.y * 0.70710678118654752f));
    v.z = a.z * 0.5f * g.z * (1.0f + erff(g.z * 0.70710678118654752f));
    v.w = a.w * 0.5f * g.w * (1.0f + erff(g.w * 0.70710678118654752f));
    stb4(O + e, v);
}

// ---------------------------------------------------------------------------
extern "C" void kernel_launch(void* const* d_in, const int* in_sizes, int n_in,
                              void* d_out, int out_size, void* d_ws, size_t ws_size,
                              hipStream_t stream) {
    const float* x     = (const float*)d_in[0];
    const float* w0    = (const float*)d_in[1];
    const float* b0    = (const float*)d_in[2];
    const float* w1    = (const float*)d_in[3];
    const float* b1    = (const float*)d_in[4];
    const float* w2    = (const float*)d_in[5];
    const float* b2    = (const float*)d_in[6];
    const float* w3    = (const float*)d_in[7];
    const float* b3    = (const float*)d_in[8];
    const float* query = (const float*)d_in[9];
    const float* lnqg  = (const float*)d_in[10];
    const float* lnqb  = (const float*)d_in[11];
    const float* lncg  = (const float*)d_in[12];
    const float* lncb  = (const float*)d_in[13];
    const float* wq    = (const float*)d_in[14];
    const float* wkv   = (const float*)d_in[15];
    const float* wo    = (const float*)d_in[16];
    const float* bo    = (const float*)d_in[17];
    const float* lnfg  = (const float*)d_in[18];
    const float* lnfb  = (const float*)d_in[19];
    const float* ffw1  = (const float*)d_in[20];
    const float* ffb1  = (const float*)d_in[21];
    const float* ffw2  = (const float*)d_in[22];
    const float* ffb2  = (const float*)d_in[23];
    float* out = (float*)d_out;
    char* wsb = (char*)d_ws;

    u16*   hA  = (u16*)(wsb + 0);
    u16*   hB  = (u16*)(wsb + 6291456);
    u16*   KVb = (u16*)(wsb + 12582912);
    float* num = (float*)(wsb + 25165824);
    float* den = (float*)(wsb + 31457280);
    u16*   qn  = (u16*)(wsb + 31473664);
    u16*   qb  = (u16*)(wsb + 31866880);
    u16*   aob = (u16*)(wsb + 32260096);
    u16*   x1b = (u16*)(wsb + 32653312);
    u16*   f0b = (u16*)(wsb + 33046528);
    u16*   f1b = (u16*)(wsb + 33439744);
    u16*   glb = (u16*)(wsb + 36585472);

    // Once: qn = LN(query) [fp32 in]; qb = qn @ wq
    ln_kernel<1><<<128, 256, 0, stream>>>(query, lnqg, lnqb, qn, 512);
    gemm_kernel<1, 0><<<dim3(8, 6), 256, 0, stream>>>(qn, wq, nullptr, nullptr, qb,
        512, 384, 384, 384, 384, 384, 0, 0);

    for (int b = 0; b < 16; ++b) {
        const float* xb   = x + (long long)b * 24576;       // 8192*3
        float*       outb = out + (long long)b * 196608;    // 512*384

        // point MLP
        layer0_kernel<<<3072, 256, 0, stream>>>(xb, w0, b0, hA, 786432);
        gemm_kernel<0, 0><<<dim3(128, 6), 256, 0, stream>>>(hA, w1, b1, nullptr, hB,
            8192, 384, 384, 384, 384, 384, 0, 1);
        gemm_kernel<0, 0><<<dim3(128, 6), 256, 0, stream>>>(hB, w2, b2, nullptr, hA,
            8192, 384, 384, 384, 384, 384, 0, 1);
        gemm_kernel<0, 0><<<dim3(128, 6), 256, 0, stream>>>(hA, w3, b3, nullptr, hB,
            8192, 384, 384, 384, 384, 384, 0, 0);          // ctx -> hB
        // kn = LN(ctx); KVb = kn @ wkv
        ln_kernel<0><<<2048, 256, 0, stream>>>(hB, lncg, lncb, hA, 8192);
        gemm_kernel<0, 0><<<dim3(128, 12), 256, 0, stream>>>(hA, wkv, nullptr, nullptr, KVb,
            8192, 768, 384, 384, 768, 768, 0, 0);
        // attention partials + reduce
        flash_part_kernel<<<dim3(32, 8), 256, 0, stream>>>(qb, KVb, num, den);
        attn_reduce_kernel<<<192, 256, 0, stream>>>(num, den, aob);
        // x1 = aob @ wo + bo + query (res fp32)
        gemm_kernel<1, 0><<<dim3(8, 6), 256, 0, stream>>>(aob, wo, bo, query, x1b,
            512, 384, 384, 384, 384, 384, 384, 0);
        // FF
        ln_kernel<0><<<128, 256, 0, stream>>>(x1b, lnfg, lnfb, f0b, 512);
        gemm_kernel<0, 0><<<dim3(8, 48), 256, 0, stream>>>(f0b, ffw1, ffb1, nullptr, f1b,
            512, 3072, 384, 384, 3072, 3072, 0, 0);
        geglu_kernel<<<768, 256, 0, stream>>>(f1b, glb, 196608);
        // out (fp32) = glb @ ffw2 + ffb2 + x1b
        gemm_kernel<0, 1><<<dim3(8, 6), 256, 0, stream>>>(glb, ffw2, ffb2, x1b, outb,
            512, 384, 1536, 1536, 384, 384, 384, 0);
    }
}

// Round 10
// 4591.339 us; speedup vs baseline: 2.1509x; 2.1509x over previous
//
#include <hip/hip_runtime.h>
#include <math.h>

// B=16, N=8192, L=512, D=384, FF=1536. INPUTS fp32, OUTPUT fp32.
// MFMA bf16 GEMMs everywhere; per-batch pipeline (R9-proven plumbing).
// Workspace (bytes, peak ~69 MB):
//   hA 0  hB 6291456  Kb 12582912  Vb 18874368  VTb 25165824
//   Sb 31457280 (fp32 16.8MB)  Pb 48234496 (bf16 8.4MB)
//   qn 56623104  qb 57016320  aob 57409536  x1b 57802752  f0b 58195968
//   f1b 58589184 (3.1MB)  glb 61734912 (1.6MB)
//   WT pool @ 63307776: w1T w2T w3T wqT (294912 ea), wkvT (589824),
//   woT (294912), ffw1T (2359296), ffw2T (1179648)  -> end ~68.9MB

typedef unsigned short u16;
typedef unsigned int   u32;
typedef __bf16 bf16_t;
typedef bf16_t bf16x8 __attribute__((ext_vector_type(8)));
typedef float  floatx4 __attribute__((ext_vector_type(4)));

__device__ __forceinline__ float b2f(u16 v) {
    return __uint_as_float(((u32)v) << 16);
}
__device__ __forceinline__ u16 f2b(float f) {
    u32 u = __float_as_uint(f);
    return (u16)((u + 0x7FFFu + ((u >> 16) & 1u)) >> 16);   // RNE
}
__device__ __forceinline__ float4 ldb4(const u16* p) {
    uint2 v = *(const uint2*)p;
    float4 f;
    f.x = __uint_as_float(v.x << 16);
    f.y = __uint_as_float(v.x & 0xFFFF0000u);
    f.z = __uint_as_float(v.y << 16);
    f.w = __uint_as_float(v.y & 0xFFFF0000u);
    return f;
}
__device__ __forceinline__ void stb4(u16* p, float4 f) {
    uint2 v;
    v.x = (u32)f2b(f.x) | ((u32)f2b(f.y) << 16);
    v.y = (u32)f2b(f.z) | ((u32)f2b(f.w) << 16);
    *(uint2*)p = v;
}

// ---------------------------------------------------------------------------
// Weight convert: W fp32 [Kd][Nd] row-major -> WT bf16 [Nd][Kd]
__global__ __launch_bounds__(256) void wconv_kernel(
    const float* __restrict__ W, u16* __restrict__ WT, int Kd, int Nd)
{
    int idx = blockIdx.x * 256 + threadIdx.x;
    if (idx >= Kd * Nd) return;
    int n = idx / Kd, k = idx - n * Kd;
    WT[idx] = f2b(W[(long long)k * Nd + n]);
}

// ---------------------------------------------------------------------------
// Layer 0: h = relu(x @ w0 + b0); x fp32 [8192][3], out bf16
__global__ __launch_bounds__(256) void layer0_kernel(
    const float* __restrict__ X, const float* __restrict__ W0,
    const float* __restrict__ B0, u16* __restrict__ H, int total4)
{
    int idx = blockIdx.x * 256 + threadIdx.x;
    if (idx >= total4) return;
    int e = idx * 4;
    int m = e / 384;
    int j = e - m * 384;
    float x0 = X[m * 3 + 0], x1 = X[m * 3 + 1], x2 = X[m * 3 + 2];
    float4 w0 = *(const float4*)(W0 + j);
    float4 w1 = *(const float4*)(W0 + 384 + j);
    float4 w2 = *(const float4*)(W0 + 768 + j);
    float4 bb = *(const float4*)(B0 + j);
    float4 v;
    v.x = fmaxf(bb.x + x0 * w0.x + x1 * w1.x + x2 * w2.x, 0.f);
    v.y = fmaxf(bb.y + x0 * w0.y + x1 * w1.y + x2 * w2.y, 0.f);
    v.z = fmaxf(bb.z + x0 * w0.z + x1 * w1.z + x2 * w2.z, 0.f);
    v.w = fmaxf(bb.w + x0 * w0.w + x1 * w1.w + x2 * w2.w, 0.f);
    stb4(H + e, v);
}

// ---------------------------------------------------------------------------
// LayerNorm; input fp32 (IN_F32=1) or bf16; g,b fp32; out bf16. 4 rows/block.
template<int IN_F32>
__global__ __launch_bounds__(256) void ln_kernel(
    const void* __restrict__ Xv, const float* __restrict__ g,
    const float* __restrict__ b, u16* __restrict__ Y, int rows)
{
    int w = threadIdx.x >> 6, lane = threadIdx.x & 63;
    int row = blockIdx.x * 4 + w;
    if (row >= rows) return;
    float v[6];
    float s = 0.f, ss = 0.f;
#pragma unroll
    for (int i = 0; i < 6; ++i) {
        int c = i * 64 + lane;
        v[i] = IN_F32 ? ((const float*)Xv)[(long long)row * 384 + c]
                      : b2f(((const u16*)Xv)[(long long)row * 384 + c]);
        s += v[i]; ss += v[i] * v[i];
    }
#pragma unroll
    for (int m = 32; m; m >>= 1) {
        s  += __shfl_xor(s, m, 64);
        ss += __shfl_xor(ss, m, 64);
    }
    float mean = s * (1.0f / 384.0f);
    float var  = ss * (1.0f / 384.0f) - mean * mean;
    float rs = rsqrtf(fmaxf(var, 0.f) + 1e-5f);
    u16* yr = Y + (long long)row * 384;
#pragma unroll
    for (int i = 0; i < 6; ++i) {
        int c = i * 64 + lane;
        yr[c] = f2b((v[i] - mean) * rs * g[c] + b[c]);
    }
}

// ---------------------------------------------------------------------------
// MFMA GEMM: C[M][N] = act(scale * A[M][K] @ WT[N][K]^T + bias) + res.
// A,WT bf16; bias fp32; res fp32/bf16; C bf16 or fp32.
// BM=128, BN=64, BK=32; 4 waves, each 32x64 via 8 mfma_f32_16x16x32_bf16.
// M%128==0, N%64==0, K%32==0.
template<int RES_F32, int OUT_F32>
__global__ __launch_bounds__(256) void gemm_mfma(
    const u16* __restrict__ A, const u16* __restrict__ WT,
    const float* __restrict__ bias, const void* __restrict__ res,
    void* __restrict__ C,
    int M, int N, int K, int lda, int ldb, int ldc, int ldres,
    float scale, int relu)
{
    __shared__ u16 As[128][56];   // pad 56 -> 112B rows (16B aligned, 2-way banks)
    __shared__ u16 Bs[64][56];
    const int tid = threadIdx.x;
    const int wv = tid >> 6, lane = tid & 63;
    const int lr = lane & 15, lq = lane >> 4;
    const int m0 = blockIdx.x * 128;
    const int n0 = blockIdx.y * 64;

    floatx4 acc[2][4];
#pragma unroll
    for (int i = 0; i < 2; ++i)
#pragma unroll
        for (int j = 0; j < 4; ++j)
            acc[i][j] = (floatx4){0.f, 0.f, 0.f, 0.f};

    for (int k0 = 0; k0 < K; k0 += 32) {
        __syncthreads();
#pragma unroll
        for (int s = 0; s < 2; ++s) {            // A tile 128x32
            int slot = tid + s * 256;
            int r = slot >> 2, sg = slot & 3;
            *(uint4*)&As[r][sg * 8] =
                *(const uint4*)(A + (long long)(m0 + r) * lda + k0 + sg * 8);
        }
        {                                        // B tile 64x32 (WT rows)
            int r = tid >> 2, sg = tid & 3;
            *(uint4*)&Bs[r][sg * 8] =
                *(const uint4*)(WT + (long long)(n0 + r) * ldb + k0 + sg * 8);
        }
        __syncthreads();
        bf16x8 a0 = *(const bf16x8*)&As[wv * 32 + lr][lq * 8];
        bf16x8 a1 = *(const bf16x8*)&As[wv * 32 + 16 + lr][lq * 8];
        bf16x8 b0 = *(const bf16x8*)&Bs[lr][lq * 8];
        bf16x8 b1 = *(const bf16x8*)&Bs[16 + lr][lq * 8];
        bf16x8 b2 = *(const bf16x8*)&Bs[32 + lr][lq * 8];
        bf16x8 b3 = *(const bf16x8*)&Bs[48 + lr][lq * 8];
        acc[0][0] = __builtin_amdgcn_mfma_f32_16x16x32_bf16(a0, b0, acc[0][0], 0, 0, 0);
        acc[0][1] = __builtin_amdgcn_mfma_f32_16x16x32_bf16(a0, b1, acc[0][1], 0, 0, 0);
        acc[0][2] = __builtin_amdgcn_mfma_f32_16x16x32_bf16(a0, b2, acc[0][2], 0, 0, 0);
        acc[0][3] = __builtin_amdgcn_mfma_f32_16x16x32_bf16(a0, b3, acc[0][3], 0, 0, 0);
        acc[1][0] = __builtin_amdgcn_mfma_f32_16x16x32_bf16(a1, b0, acc[1][0], 0, 0, 0);
        acc[1][1] = __builtin_amdgcn_mfma_f32_16x16x32_bf16(a1, b1, acc[1][1], 0, 0, 0);
        acc[1][2] = __builtin_amdgcn_mfma_f32_16x16x32_bf16(a1, b2, acc[1][2], 0, 0, 0);
        acc[1][3] = __builtin_amdgcn_mfma_f32_16x16x32_bf16(a1, b3, acc[1][3], 0, 0, 0);
    }

    // epilogue: C[m][n], row=(lane>>4)*4+reg, col=lane&15 within each 16x16
#pragma unroll
    for (int ms = 0; ms < 2; ++ms) {
#pragma unroll
        for (int ns = 0; ns < 4; ++ns) {
            int col = n0 + ns * 16 + lr;
            float bi = bias ? bias[col] : 0.f;
#pragma unroll
            for (int r = 0; r < 4; ++r) {
                int m = m0 + wv * 32 + ms * 16 + lq * 4 + r;
                float v = acc[ms][ns][r] * scale + bi;
                if (relu) v = fmaxf(v, 0.f);
                if (res) {
                    long long ro = (long long)m * ldres + col;
                    v += RES_F32 ? ((const float*)res)[ro]
                                 : b2f(((const u16*)res)[ro]);
                }
                long long co = (long long)m * ldc + col;
                if (OUT_F32) ((float*)C)[co] = v;
                else         ((u16*)C)[co] = f2b(v);
            }
        }
    }
}

// ---------------------------------------------------------------------------
// Transpose V [8192][384] bf16 -> VT [384][8192] bf16. 64x64 LDS tiles.
__global__ __launch_bounds__(256) void transpose_kernel(
    const u16* __restrict__ V, u16* __restrict__ VT)
{
    __shared__ u16 t[64][72];
    const int tid = threadIdx.x;
    const int n0 = blockIdx.x * 64;
    const int d0 = blockIdx.y * 64;
#pragma unroll
    for (int s = 0; s < 4; ++s) {
        int slot = tid + s * 256;
        int r = slot >> 4, q = slot & 15;
        *(ushort4*)&t[r][q * 4] =
            *(const ushort4*)(V + (long long)(n0 + r) * 384 + d0 + q * 4);
    }
    __syncthreads();
#pragma unroll
    for (int s = 0; s < 4; ++s) {
        int slot = tid + s * 256;
        int dr = slot >> 4, q = slot & 15;
        ushort4 v;
        v.x = t[q * 4 + 0][dr];
        v.y = t[q * 4 + 1][dr];
        v.z = t[q * 4 + 2][dr];
        v.w = t[q * 4 + 3][dr];
        *(ushort4*)(VT + (long long)(d0 + dr) * 8192 + n0 + q * 4) = v;
    }
}

// ---------------------------------------------------------------------------
// Softmax rows of 8192: S fp32 in -> P bf16 out (normalized). 1 block/row.
__global__ __launch_bounds__(256) void softmax_kernel(
    const float* __restrict__ S, u16* __restrict__ P)
{
    __shared__ float red[4];
    const int tid = threadIdx.x;
    const float* row = S + (long long)blockIdx.x * 8192;
    float4 e[8];
    float ls = 0.f;
#pragma unroll
    for (int c = 0; c < 8; ++c) {
        float4 v = *(const float4*)(row + c * 1024 + tid * 4);
        v.x = __expf(fminf(fmaxf(v.x, -60.f), 60.f));
        v.y = __expf(fminf(fmaxf(v.y, -60.f), 60.f));
        v.z = __expf(fminf(fmaxf(v.z, -60.f), 60.f));
        v.w = __expf(fminf(fmaxf(v.w, -60.f), 60.f));
        e[c] = v;
        ls += v.x + v.y + v.z + v.w;
    }
#pragma unroll
    for (int m = 32; m; m >>= 1) ls += __shfl_xor(ls, m, 64);
    if ((tid & 63) == 0) red[tid >> 6] = ls;
    __syncthreads();
    float inv = 1.0f / (red[0] + red[1] + red[2] + red[3]);
    u16* prow = P + (long long)blockIdx.x * 8192;
#pragma unroll
    for (int c = 0; c < 8; ++c) {
        float4 v = e[c];
        v.x *= inv; v.y *= inv; v.z *= inv; v.w *= inv;
        stb4(prow + c * 1024 + tid * 4, v);
    }
}

// ---------------------------------------------------------------------------
// GEGLU: O[m][j] = F[m][j] * gelu_exact(F[m][1536+j]); F bf16 [512][3072]
__global__ __launch_bounds__(256) void geglu_kernel(
    const u16* __restrict__ F, u16* __restrict__ O, int total4)
{
    int idx = blockIdx.x * 256 + threadIdx.x;
    if (idx >= total4) return;
    int e = idx * 4;
    int m = e / 1536;
    int j = e - m * 1536;
    float4 a = ldb4(F + (long long)m * 3072 + j);
    float4 g = ldb4(F + (long long)m * 3072 + 1536 + j);
    float4 v;
    v.x = a.x * 0.5f * g.x * (1.0f + erff(g.x * 0.70710678118654752f));
    v.y = a.y * 0.5f * g.y * (1.0f + erff(g.y * 0.70710678118654752f));
    v.z = a.z * 0.5f * g.z * (1.0f + erff(g.z * 0.70710678118654752f));
    v.w = a.w * 0.5f * g.w * (1.0f + erff(g.w * 0.70710678118654752f));
    stb4(O + e, v);
}

// ---------------------------------------------------------------------------
extern "C" void kernel_launch(void* const* d_in, const int* in_sizes, int n_in,
                              void* d_out, int out_size, void* d_ws, size_t ws_size,
                              hipStream_t stream) {
    const float* x     = (const float*)d_in[0];
    const float* w0    = (const float*)d_in[1];
    const float* b0    = (const float*)d_in[2];
    const float* w1    = (const float*)d_in[3];
    const float* b1    = (const float*)d_in[4];
    const float* w2    = (const float*)d_in[5];
    const float* b2    = (const float*)d_in[6];
    const float* w3    = (const float*)d_in[7];
    const float* b3    = (const float*)d_in[8];
    const float* query = (const float*)d_in[9];
    const float* lnqg  = (const float*)d_in[10];
    const float* lnqb  = (const float*)d_in[11];
    const float* lncg  = (const float*)d_in[12];
    const float* lncb  = (const float*)d_in[13];
    const float* wq    = (const float*)d_in[14];
    const float* wkv   = (const float*)d_in[15];
    const float* wo    = (const float*)d_in[16];
    const float* bo    = (const float*)d_in[17];
    const float* lnfg  = (const float*)d_in[18];
    const float* lnfb  = (const float*)d_in[19];
    const float* ffw1  = (const float*)d_in[20];
    const float* ffb1  = (const float*)d_in[21];
    const float* ffw2  = (const float*)d_in[22];
    const float* ffb2  = (const float*)d_in[23];
    float* out = (float*)d_out;
    char* wsb = (char*)d_ws;

    u16*   hA   = (u16*)(wsb + 0);
    u16*   hB   = (u16*)(wsb + 6291456);
    u16*   Kb   = (u16*)(wsb + 12582912);
    u16*   Vb   = (u16*)(wsb + 18874368);
    u16*   VTb  = (u16*)(wsb + 25165824);
    float* Sb   = (float*)(wsb + 31457280);
    u16*   Pb   = (u16*)(wsb + 48234496);
    u16*   qn   = (u16*)(wsb + 56623104);
    u16*   qb   = (u16*)(wsb + 57016320);
    u16*   aob  = (u16*)(wsb + 57409536);
    u16*   x1b  = (u16*)(wsb + 57802752);
    u16*   f0b  = (u16*)(wsb + 58195968);
    u16*   f1b  = (u16*)(wsb + 58589184);
    u16*   glb  = (u16*)(wsb + 61734912);
    u16*   w1T   = (u16*)(wsb + 63307776);
    u16*   w2T   = (u16*)(wsb + 63602688);
    u16*   w3T   = (u16*)(wsb + 63897600);
    u16*   wqT   = (u16*)(wsb + 64192512);
    u16*   wkvT  = (u16*)(wsb + 64487424);   // [768][384]; rows 384.. = WvT
    u16*   woT   = (u16*)(wsb + 65077248);
    u16*   ffw1T = (u16*)(wsb + 65372160);   // [3072][384]
    u16*   ffw2T = (u16*)(wsb + 67731456);   // [384][1536]

    auto G = [&](const u16* A, const u16* WTp, const float* bias, const void* res,
                 void* C, int M, int N, int K, int lda, int ldb, int ldc, int ldres,
                 float scale, int relu, int resf32, int outf32) {
        dim3 grid(M / 128, N / 64);
        if (outf32) {
            gemm_mfma<0, 1><<<grid, 256, 0, stream>>>(A, WTp, bias, res, C,
                M, N, K, lda, ldb, ldc, ldres, scale, relu);
        } else if (resf32) {
            gemm_mfma<1, 0><<<grid, 256, 0, stream>>>(A, WTp, bias, res, C,
                M, N, K, lda, ldb, ldc, ldres, scale, relu);
        } else {
            gemm_mfma<0, 0><<<grid, 256, 0, stream>>>(A, WTp, bias, res, C,
                M, N, K, lda, ldb, ldc, ldres, scale, relu);
        }
    };

    // ---- weight conversions (once) ----
    wconv_kernel<<<576,  256, 0, stream>>>(w1,   w1T,   384, 384);
    wconv_kernel<<<576,  256, 0, stream>>>(w2,   w2T,   384, 384);
    wconv_kernel<<<576,  256, 0, stream>>>(w3,   w3T,   384, 384);
    wconv_kernel<<<576,  256, 0, stream>>>(wq,   wqT,   384, 384);
    wconv_kernel<<<1152, 256, 0, stream>>>(wkv,  wkvT,  384, 768);
    wconv_kernel<<<576,  256, 0, stream>>>(wo,   woT,   384, 384);
    wconv_kernel<<<4608, 256, 0, stream>>>(ffw1, ffw1T, 384, 3072);
    wconv_kernel<<<2304, 256, 0, stream>>>(ffw2, ffw2T, 1536, 384);

    // ---- q path (once) ----
    ln_kernel<1><<<128, 256, 0, stream>>>(query, lnqg, lnqb, qn, 512);
    G(qn, wqT, nullptr, nullptr, qb, 512, 384, 384, 384, 384, 384, 0, 1.f, 0, 0, 0);

    for (int b = 0; b < 16; ++b) {
        const float* xb   = x + (long long)b * 24576;
        float*       outb = out + (long long)b * 196608;

        layer0_kernel<<<3072, 256, 0, stream>>>(xb, w0, b0, hA, 786432);
        G(hA, w1T, b1, nullptr, hB, 8192, 384, 384, 384, 384, 384, 0, 1.f, 1, 0, 0);
        G(hB, w2T, b2, nullptr, hA, 8192, 384, 384, 384, 384, 384, 0, 1.f, 1, 0, 0);
        G(hA, w3T, b3, nullptr, hB, 8192, 384, 384, 384, 384, 384, 0, 1.f, 0, 0, 0);
        ln_kernel<0><<<2048, 256, 0, stream>>>(hB, lncg, lncb, hA, 8192);
        G(hA, wkvT,          nullptr, nullptr, Kb, 8192, 384, 384, 384, 384, 384, 0, 1.f, 0, 0, 0);
        G(hA, wkvT + 147456, nullptr, nullptr, Vb, 8192, 384, 384, 384, 384, 384, 0, 1.f, 0, 0, 0);
        transpose_kernel<<<dim3(128, 6), 256, 0, stream>>>(Vb, VTb);
        // S = qb @ Kb^T * scale (fp32 out)
        G(qb, Kb, nullptr, nullptr, Sb, 512, 8192, 384, 384, 384, 8192, 0,
          0.05103103630798288f, 0, 0, 1);
        softmax_kernel<<<512, 256, 0, stream>>>(Sb, Pb);
        // AO = P @ V  (via VT [384][8192])
        G(Pb, VTb, nullptr, nullptr, aob, 512, 384, 8192, 8192, 8192, 384, 0, 1.f, 0, 0, 0);
        // x1 = AO @ wo + bo + query (fp32 res)
        G(aob, woT, bo, query, x1b, 512, 384, 384, 384, 384, 384, 384, 1.f, 0, 1, 0);
        ln_kernel<0><<<128, 256, 0, stream>>>(x1b, lnfg, lnfb, f0b, 512);
        G(f0b, ffw1T, ffb1, nullptr, f1b, 512, 3072, 384, 384, 384, 3072, 0, 1.f, 0, 0, 0);
        geglu_kernel<<<768, 256, 0, stream>>>(f1b, glb, 196608);
        // out fp32 = glb @ ffw2 + ffb2 + x1b(bf16)
        G(glb, ffw2T, ffb2, x1b, outb, 512, 384, 1536, 1536, 1536, 384, 384, 1.f, 0, 0, 1);
    }
}

// Round 11
// 1942.352 us; speedup vs baseline: 5.0842x; 2.3638x over previous
//
#include <hip/hip_runtime.h>
#include <math.h>

// B=16, N=8192, L=512, D=384, FF=1536. INPUTS fp32, OUTPUT fp32.
// MFMA bf16 GEMMs; per-batch phase 1 (MLP+KV+attention), batched phase 2.
// Workspace (bytes, peak ~96.6 MB):
//   hA 0  hB 6291456  Kb 12582912  VTb 18874368  Pb 25165824 (8.4MB)
//   part 33554432 (fp32 [16][512][384] = 12.6MB)  ao_all 46137344
//   x1_all 52428800  f0_all 58720256  gl_all 65011712 (25.2MB)
//   qn 90177536  qb 90570752  den_all 90963968 (32KB)
//   WT pool 90996736..96600064

typedef unsigned short u16;
typedef unsigned int   u32;
typedef __bf16 bf16_t;
typedef bf16_t bf16x8 __attribute__((ext_vector_type(8)));
typedef float  floatx4 __attribute__((ext_vector_type(4)));

__device__ __forceinline__ float b2f(u16 v) {
    return __uint_as_float(((u32)v) << 16);
}
__device__ __forceinline__ u16 f2b(float f) {
    u32 u = __float_as_uint(f);
    return (u16)((u + 0x7FFFu + ((u >> 16) & 1u)) >> 16);   // RNE
}
__device__ __forceinline__ float4 ldb4(const u16* p) {
    uint2 v = *(const uint2*)p;
    float4 f;
    f.x = __uint_as_float(v.x << 16);
    f.y = __uint_as_float(v.x & 0xFFFF0000u);
    f.z = __uint_as_float(v.y << 16);
    f.w = __uint_as_float(v.y & 0xFFFF0000u);
    return f;
}
__device__ __forceinline__ void stb4(u16* p, float4 f) {
    uint2 v;
    v.x = (u32)f2b(f.x) | ((u32)f2b(f.y) << 16);
    v.y = (u32)f2b(f.z) | ((u32)f2b(f.w) << 16);
    *(uint2*)p = v;
}

// ---------------------------------------------------------------------------
// Weight convert: W fp32 [Kd][Nd] -> WT bf16 [Nd][Kd]
__global__ __launch_bounds__(256) void wconv_kernel(
    const float* __restrict__ W, u16* __restrict__ WT, int Kd, int Nd)
{
    int idx = blockIdx.x * 256 + threadIdx.x;
    if (idx >= Kd * Nd) return;
    int n = idx / Kd, k = idx - n * Kd;
    WT[idx] = f2b(W[(long long)k * Nd + n]);
}

// ---------------------------------------------------------------------------
// Layer 0: h = relu(x @ w0 + b0); x fp32 [8192][3], out bf16
__global__ __launch_bounds__(256) void layer0_kernel(
    const float* __restrict__ X, const float* __restrict__ W0,
    const float* __restrict__ B0, u16* __restrict__ H, int total4)
{
    int idx = blockIdx.x * 256 + threadIdx.x;
    if (idx >= total4) return;
    int e = idx * 4;
    int m = e / 384;
    int j = e - m * 384;
    float x0 = X[m * 3 + 0], x1 = X[m * 3 + 1], x2 = X[m * 3 + 2];
    float4 w0 = *(const float4*)(W0 + j);
    float4 w1 = *(const float4*)(W0 + 384 + j);
    float4 w2 = *(const float4*)(W0 + 768 + j);
    float4 bb = *(const float4*)(B0 + j);
    float4 v;
    v.x = fmaxf(bb.x + x0 * w0.x + x1 * w1.x + x2 * w2.x, 0.f);
    v.y = fmaxf(bb.y + x0 * w0.y + x1 * w1.y + x2 * w2.y, 0.f);
    v.z = fmaxf(bb.z + x0 * w0.z + x1 * w1.z + x2 * w2.z, 0.f);
    v.w = fmaxf(bb.w + x0 * w0.w + x1 * w1.w + x2 * w2.w, 0.f);
    stb4(H + e, v);
}

// ---------------------------------------------------------------------------
// LayerNorm; input fp32 (IN_F32=1) or bf16; g,b fp32; out bf16. 4 rows/block.
template<int IN_F32>
__global__ __launch_bounds__(256) void ln_kernel(
    const void* __restrict__ Xv, const float* __restrict__ g,
    const float* __restrict__ b, u16* __restrict__ Y, int rows)
{
    int w = threadIdx.x >> 6, lane = threadIdx.x & 63;
    int row = blockIdx.x * 4 + w;
    if (row >= rows) return;
    float v[6];
    float s = 0.f, ss = 0.f;
#pragma unroll
    for (int i = 0; i < 6; ++i) {
        int c = i * 64 + lane;
        v[i] = IN_F32 ? ((const float*)Xv)[(long long)row * 384 + c]
                      : b2f(((const u16*)Xv)[(long long)row * 384 + c]);
        s += v[i]; ss += v[i] * v[i];
    }
#pragma unroll
    for (int m = 32; m; m >>= 1) {
        s  += __shfl_xor(s, m, 64);
        ss += __shfl_xor(ss, m, 64);
    }
    float mean = s * (1.0f / 384.0f);
    float var  = ss * (1.0f / 384.0f) - mean * mean;
    float rs = rsqrtf(fmaxf(var, 0.f) + 1e-5f);
    u16* yr = Y + (long long)row * 384;
#pragma unroll
    for (int i = 0; i < 6; ++i) {
        int c = i * 64 + lane;
        yr[c] = f2b((v[i] - mean) * rs * g[c] + b[c]);
    }
}

// ---------------------------------------------------------------------------
// Core MFMA tile loop as a macro-like inline: BM=128, BN=64, BK=32, 4 waves.
// A[M][K] lda, WT[N][K] ldb -> acc[2][4] per wave (rows wv*32+ms*16+lq*4+r,
// cols ns*16+lr). C/D layout verified (learn_hip m89/m91).

// Generic GEMM: C = act(scale*A@WT^T + bias) + res. resmask broadcasts rows.
template<int RES_F32, int OUT_F32>
__global__ __launch_bounds__(256) void gemm_mfma(
    const u16* __restrict__ A, const u16* __restrict__ WT,
    const float* __restrict__ bias, const void* __restrict__ res,
    void* __restrict__ C,
    int M, int N, int K, int lda, int ldb, int ldc, int ldres,
    float scale, int relu, int resmask)
{
    __shared__ u16 As[128][56];
    __shared__ u16 Bs[64][56];
    const int tid = threadIdx.x;
    const int wv = tid >> 6, lane = tid & 63;
    const int lr = lane & 15, lq = lane >> 4;
    const int m0 = blockIdx.x * 128;
    const int n0 = blockIdx.y * 64;

    floatx4 acc[2][4];
#pragma unroll
    for (int i = 0; i < 2; ++i)
#pragma unroll
        for (int j = 0; j < 4; ++j)
            acc[i][j] = (floatx4){0.f, 0.f, 0.f, 0.f};

    for (int k0 = 0; k0 < K; k0 += 32) {
        __syncthreads();
#pragma unroll
        for (int s = 0; s < 2; ++s) {
            int slot = tid + s * 256;
            int r = slot >> 2, sg = slot & 3;
            *(uint4*)&As[r][sg * 8] =
                *(const uint4*)(A + (long long)(m0 + r) * lda + k0 + sg * 8);
        }
        {
            int r = tid >> 2, sg = tid & 3;
            *(uint4*)&Bs[r][sg * 8] =
                *(const uint4*)(WT + (long long)(n0 + r) * ldb + k0 + sg * 8);
        }
        __syncthreads();
        bf16x8 a0 = *(const bf16x8*)&As[wv * 32 + lr][lq * 8];
        bf16x8 a1 = *(const bf16x8*)&As[wv * 32 + 16 + lr][lq * 8];
        bf16x8 b0 = *(const bf16x8*)&Bs[lr][lq * 8];
        bf16x8 b1 = *(const bf16x8*)&Bs[16 + lr][lq * 8];
        bf16x8 b2 = *(const bf16x8*)&Bs[32 + lr][lq * 8];
        bf16x8 b3 = *(const bf16x8*)&Bs[48 + lr][lq * 8];
        acc[0][0] = __builtin_amdgcn_mfma_f32_16x16x32_bf16(a0, b0, acc[0][0], 0, 0, 0);
        acc[0][1] = __builtin_amdgcn_mfma_f32_16x16x32_bf16(a0, b1, acc[0][1], 0, 0, 0);
        acc[0][2] = __builtin_amdgcn_mfma_f32_16x16x32_bf16(a0, b2, acc[0][2], 0, 0, 0);
        acc[0][3] = __builtin_amdgcn_mfma_f32_16x16x32_bf16(a0, b3, acc[0][3], 0, 0, 0);
        acc[1][0] = __builtin_amdgcn_mfma_f32_16x16x32_bf16(a1, b0, acc[1][0], 0, 0, 0);
        acc[1][1] = __builtin_amdgcn_mfma_f32_16x16x32_bf16(a1, b1, acc[1][1], 0, 0, 0);
        acc[1][2] = __builtin_amdgcn_mfma_f32_16x16x32_bf16(a1, b2, acc[1][2], 0, 0, 0);
        acc[1][3] = __builtin_amdgcn_mfma_f32_16x16x32_bf16(a1, b3, acc[1][3], 0, 0, 0);
    }

#pragma unroll
    for (int ms = 0; ms < 2; ++ms) {
#pragma unroll
        for (int ns = 0; ns < 4; ++ns) {
            int col = n0 + ns * 16 + lr;
            float bi = bias ? bias[col] : 0.f;
#pragma unroll
            for (int r = 0; r < 4; ++r) {
                int m = m0 + wv * 32 + ms * 16 + lq * 4 + r;
                float v = acc[ms][ns][r] * scale + bi;
                if (relu) v = fmaxf(v, 0.f);
                if (res) {
                    long long ro = (long long)(m & resmask) * ldres + col;
                    v += RES_F32 ? ((const float*)res)[ro]
                                 : b2f(((const u16*)res)[ro]);
                }
                long long co = (long long)m * ldc + col;
                if (OUT_F32) ((float*)C)[co] = v;
                else         ((u16*)C)[co] = f2b(v);
            }
        }
    }
}

// ---------------------------------------------------------------------------
// S-with-exp GEMM: P = exp(clamp(scale * q @ K^T)) (bf16), den += row sums.
__global__ __launch_bounds__(256) void gemm_exp(
    const u16* __restrict__ A, const u16* __restrict__ WT,
    u16* __restrict__ P, float* __restrict__ den,
    int K, int lda, int ldb, int ldc, float scale)
{
    __shared__ u16 As[128][56];
    __shared__ u16 Bs[64][56];
    const int tid = threadIdx.x;
    const int wv = tid >> 6, lane = tid & 63;
    const int lr = lane & 15, lq = lane >> 4;
    const int m0 = blockIdx.x * 128;
    const int n0 = blockIdx.y * 64;

    floatx4 acc[2][4];
#pragma unroll
    for (int i = 0; i < 2; ++i)
#pragma unroll
        for (int j = 0; j < 4; ++j)
            acc[i][j] = (floatx4){0.f, 0.f, 0.f, 0.f};

    for (int k0 = 0; k0 < K; k0 += 32) {
        __syncthreads();
#pragma unroll
        for (int s = 0; s < 2; ++s) {
            int slot = tid + s * 256;
            int r = slot >> 2, sg = slot & 3;
            *(uint4*)&As[r][sg * 8] =
                *(const uint4*)(A + (long long)(m0 + r) * lda + k0 + sg * 8);
        }
        {
            int r = tid >> 2, sg = tid & 3;
            *(uint4*)&Bs[r][sg * 8] =
                *(const uint4*)(WT + (long long)(n0 + r) * ldb + k0 + sg * 8);
        }
        __syncthreads();
        bf16x8 a0 = *(const bf16x8*)&As[wv * 32 + lr][lq * 8];
        bf16x8 a1 = *(const bf16x8*)&As[wv * 32 + 16 + lr][lq * 8];
        bf16x8 b0 = *(const bf16x8*)&Bs[lr][lq * 8];
        bf16x8 b1 = *(const bf16x8*)&Bs[16 + lr][lq * 8];
        bf16x8 b2 = *(const bf16x8*)&Bs[32 + lr][lq * 8];
        bf16x8 b3 = *(const bf16x8*)&Bs[48 + lr][lq * 8];
        acc[0][0] = __builtin_amdgcn_mfma_f32_16x16x32_bf16(a0, b0, acc[0][0], 0, 0, 0);
        acc[0][1] = __builtin_amdgcn_mfma_f32_16x16x32_bf16(a0, b1, acc[0][1], 0, 0, 0);
        acc[0][2] = __builtin_amdgcn_mfma_f32_16x16x32_bf16(a0, b2, acc[0][2], 0, 0, 0);
        acc[0][3] = __builtin_amdgcn_mfma_f32_16x16x32_bf16(a0, b3, acc[0][3], 0, 0, 0);
        acc[1][0] = __builtin_amdgcn_mfma_f32_16x16x32_bf16(a1, b0, acc[1][0], 0, 0, 0);
        acc[1][1] = __builtin_amdgcn_mfma_f32_16x16x32_bf16(a1, b1, acc[1][1], 0, 0, 0);
        acc[1][2] = __builtin_amdgcn_mfma_f32_16x16x32_bf16(a1, b2, acc[1][2], 0, 0, 0);
        acc[1][3] = __builtin_amdgcn_mfma_f32_16x16x32_bf16(a1, b3, acc[1][3], 0, 0, 0);
    }

    float srow[2][4] = {};
#pragma unroll
    for (int ms = 0; ms < 2; ++ms) {
#pragma unroll
        for (int ns = 0; ns < 4; ++ns) {
            int col = n0 + ns * 16 + lr;
#pragma unroll
            for (int r = 0; r < 4; ++r) {
                int m = m0 + wv * 32 + ms * 16 + lq * 4 + r;
                float l = acc[ms][ns][r] * scale;
                l = fminf(fmaxf(l, -60.f), 60.f);
                float p = __expf(l);
                ((u16*)P)[(long long)m * ldc + col] = f2b(p);
                srow[ms][r] += p;
            }
        }
    }
#pragma unroll
    for (int ms = 0; ms < 2; ++ms)
#pragma unroll
        for (int r = 0; r < 4; ++r) {
            float s = srow[ms][r];
            s += __shfl_xor(s, 1, 64);
            s += __shfl_xor(s, 2, 64);
            s += __shfl_xor(s, 4, 64);
            s += __shfl_xor(s, 8, 64);
            if (lr == 0)
                atomicAdd(&den[m0 + wv * 32 + ms * 16 + lq * 4 + r], s);
        }
}

// ---------------------------------------------------------------------------
// Split-K PV: part[z][m][n] = P[m, z*512..] @ VT[n][z*512..]^T (fp32 partials)
__global__ __launch_bounds__(256) void gemm_pv(
    const u16* __restrict__ A, const u16* __restrict__ WT,
    float* __restrict__ part, int lda, int ldb)
{
    __shared__ u16 As[128][56];
    __shared__ u16 Bs[64][56];
    const int tid = threadIdx.x;
    const int wv = tid >> 6, lane = tid & 63;
    const int lr = lane & 15, lq = lane >> 4;
    const int m0 = blockIdx.x * 128;
    const int n0 = blockIdx.y * 64;
    const int z = blockIdx.z;

    floatx4 acc[2][4];
#pragma unroll
    for (int i = 0; i < 2; ++i)
#pragma unroll
        for (int j = 0; j < 4; ++j)
            acc[i][j] = (floatx4){0.f, 0.f, 0.f, 0.f};

    for (int k0 = z * 512; k0 < (z + 1) * 512; k0 += 32) {
        __syncthreads();
#pragma unroll
        for (int s = 0; s < 2; ++s) {
            int slot = tid + s * 256;
            int r = slot >> 2, sg = slot & 3;
            *(uint4*)&As[r][sg * 8] =
                *(const uint4*)(A + (long long)(m0 + r) * lda + k0 + sg * 8);
        }
        {
            int r = tid >> 2, sg = tid & 3;
            *(uint4*)&Bs[r][sg * 8] =
                *(const uint4*)(WT + (long long)(n0 + r) * ldb + k0 + sg * 8);
        }
        __syncthreads();
        bf16x8 a0 = *(const bf16x8*)&As[wv * 32 + lr][lq * 8];
        bf16x8 a1 = *(const bf16x8*)&As[wv * 32 + 16 + lr][lq * 8];
        bf16x8 b0 = *(const bf16x8*)&Bs[lr][lq * 8];
        bf16x8 b1 = *(const bf16x8*)&Bs[16 + lr][lq * 8];
        bf16x8 b2 = *(const bf16x8*)&Bs[32 + lr][lq * 8];
        bf16x8 b3 = *(const bf16x8*)&Bs[48 + lr][lq * 8];
        acc[0][0] = __builtin_amdgcn_mfma_f32_16x16x32_bf16(a0, b0, acc[0][0], 0, 0, 0);
        acc[0][1] = __builtin_amdgcn_mfma_f32_16x16x32_bf16(a0, b1, acc[0][1], 0, 0, 0);
        acc[0][2] = __builtin_amdgcn_mfma_f32_16x16x32_bf16(a0, b2, acc[0][2], 0, 0, 0);
        acc[0][3] = __builtin_amdgcn_mfma_f32_16x16x32_bf16(a0, b3, acc[0][3], 0, 0, 0);
        acc[1][0] = __builtin_amdgcn_mfma_f32_16x16x32_bf16(a1, b0, acc[1][0], 0, 0, 0);
        acc[1][1] = __builtin_amdgcn_mfma_f32_16x16x32_bf16(a1, b1, acc[1][1], 0, 0, 0);
        acc[1][2] = __builtin_amdgcn_mfma_f32_16x16x32_bf16(a1, b2, acc[1][2], 0, 0, 0);
        acc[1][3] = __builtin_amdgcn_mfma_f32_16x16x32_bf16(a1, b3, acc[1][3], 0, 0, 0);
    }

    float* pz = part + (long long)z * 512 * 384;
#pragma unroll
    for (int ms = 0; ms < 2; ++ms)
#pragma unroll
        for (int ns = 0; ns < 4; ++ns) {
            int col = n0 + ns * 16 + lr;
#pragma unroll
            for (int r = 0; r < 4; ++r) {
                int m = m0 + wv * 32 + ms * 16 + lq * 4 + r;
                pz[(long long)m * 384 + col] = acc[ms][ns][r];
            }
        }
}

// ---------------------------------------------------------------------------
// PV reduce: ao[q][d] = (sum_z part[z][q][d]) / den[q]  -> bf16
__global__ __launch_bounds__(256) void pv_reduce_kernel(
    const float* __restrict__ part, const float* __restrict__ den,
    u16* __restrict__ AO)
{
    int idx = blockIdx.x * 256 + threadIdx.x;   // 49152 = 512*96
    int q = idx / 96, j = (idx - q * 96) * 4;
    float4 s = make_float4(0.f, 0.f, 0.f, 0.f);
#pragma unroll
    for (int z = 0; z < 16; ++z) {
        float4 v = *(const float4*)(part + ((long long)z * 512 + q) * 384 + j);
        s.x += v.x; s.y += v.y; s.z += v.z; s.w += v.w;
    }
    float inv = 1.0f / den[q];
    s.x *= inv; s.y *= inv; s.z *= inv; s.w *= inv;
    stb4(AO + (long long)q * 384 + j, s);
}

// ---------------------------------------------------------------------------
// FF1 + GEGLU fused: gl[m][n] = a * gelu(g), a = f0@W1a + b1a, g = f0@W1g + b1g
// WT = ffw1T [3072][384]; cols n use row n (a) and row 1536+n (g).
__global__ __launch_bounds__(256) void gemm_ff1_geglu(
    const u16* __restrict__ A, const u16* __restrict__ WT,
    const float* __restrict__ bias, u16* __restrict__ C,
    int K, int lda, int ldb, int ldc)
{
    __shared__ u16 As[128][56];
    __shared__ u16 Bs[128][56];   // rows 0-63: a-cols; rows 64-127: g-cols
    const int tid = threadIdx.x;
    const int wv = tid >> 6, lane = tid & 63;
    const int lr = lane & 15, lq = lane >> 4;
    const int m0 = blockIdx.x * 128;
    const int n0 = blockIdx.y * 64;

    floatx4 accA[2][4], accG[2][4];
#pragma unroll
    for (int i = 0; i < 2; ++i)
#pragma unroll
        for (int j = 0; j < 4; ++j) {
            accA[i][j] = (floatx4){0.f, 0.f, 0.f, 0.f};
            accG[i][j] = (floatx4){0.f, 0.f, 0.f, 0.f};
        }

    for (int k0 = 0; k0 < K; k0 += 32) {
        __syncthreads();
#pragma unroll
        for (int s = 0; s < 2; ++s) {
            int slot = tid + s * 256;
            int r = slot >> 2, sg = slot & 3;
            *(uint4*)&As[r][sg * 8] =
                *(const uint4*)(A + (long long)(m0 + r) * lda + k0 + sg * 8);
        }
#pragma unroll
        for (int s = 0; s < 2; ++s) {
            int slot = tid + s * 256;
            int r = slot >> 2, sg = slot & 3;
            int wrow = (r < 64) ? (n0 + r) : (1536 + n0 + r - 64);
            *(uint4*)&Bs[r][sg * 8] =
                *(const uint4*)(WT + (long long)wrow * ldb + k0 + sg * 8);
        }
        __syncthreads();
        bf16x8 a0 = *(const bf16x8*)&As[wv * 32 + lr][lq * 8];
        bf16x8 a1 = *(const bf16x8*)&As[wv * 32 + 16 + lr][lq * 8];
#pragma unroll
        for (int ns = 0; ns < 4; ++ns) {
            bf16x8 bA = *(const bf16x8*)&Bs[ns * 16 + lr][lq * 8];
            bf16x8 bG = *(const bf16x8*)&Bs[64 + ns * 16 + lr][lq * 8];
            accA[0][ns] = __builtin_amdgcn_mfma_f32_16x16x32_bf16(a0, bA, accA[0][ns], 0, 0, 0);
            accA[1][ns] = __builtin_amdgcn_mfma_f32_16x16x32_bf16(a1, bA, accA[1][ns], 0, 0, 0);
            accG[0][ns] = __builtin_amdgcn_mfma_f32_16x16x32_bf16(a0, bG, accG[0][ns], 0, 0, 0);
            accG[1][ns] = __builtin_amdgcn_mfma_f32_16x16x32_bf16(a1, bG, accG[1][ns], 0, 0, 0);
        }
    }

#pragma unroll
    for (int ms = 0; ms < 2; ++ms)
#pragma unroll
        for (int ns = 0; ns < 4; ++ns) {
            int col = n0 + ns * 16 + lr;
            float ba = bias[col];
            float bg = bias[1536 + col];
#pragma unroll
            for (int r = 0; r < 4; ++r) {
                int m = m0 + wv * 32 + ms * 16 + lq * 4 + r;
                float a = accA[ms][ns][r] + ba;
                float g = accG[ms][ns][r] + bg;
                float v = a * 0.5f * g * (1.0f + erff(g * 0.70710678118654752f));
                C[(long long)m * ldc + col] = f2b(v);
            }
        }
}

// ---------------------------------------------------------------------------
extern "C" void kernel_launch(void* const* d_in, const int* in_sizes, int n_in,
                              void* d_out, int out_size, void* d_ws, size_t ws_size,
                              hipStream_t stream) {
    const float* x     = (const float*)d_in[0];
    const float* w0    = (const float*)d_in[1];
    const float* b0    = (const float*)d_in[2];
    const float* w1    = (const float*)d_in[3];
    const float* b1    = (const float*)d_in[4];
    const float* w2    = (const float*)d_in[5];
    const float* b2    = (const float*)d_in[6];
    const float* w3    = (const float*)d_in[7];
    const float* b3    = (const float*)d_in[8];
    const float* query = (const float*)d_in[9];
    const float* lnqg  = (const float*)d_in[10];
    const float* lnqb  = (const float*)d_in[11];
    const float* lncg  = (const float*)d_in[12];
    const float* lncb  = (const float*)d_in[13];
    const float* wq    = (const float*)d_in[14];
    const float* wkv   = (const float*)d_in[15];
    const float* wo    = (const float*)d_in[16];
    const float* bo    = (const float*)d_in[17];
    const float* lnfg  = (const float*)d_in[18];
    const float* lnfb  = (const float*)d_in[19];
    const float* ffw1  = (const float*)d_in[20];
    const float* ffb1  = (const float*)d_in[21];
    const float* ffw2  = (const float*)d_in[22];
    const float* ffb2  = (const float*)d_in[23];
    float* out = (float*)d_out;
    char* wsb = (char*)d_ws;

    u16*   hA     = (u16*)(wsb + 0);
    u16*   hB     = (u16*)(wsb + 6291456);
    u16*   Kb     = (u16*)(wsb + 12582912);
    u16*   VTb    = (u16*)(wsb + 18874368);
    u16*   Pb     = (u16*)(wsb + 25165824);    // 512x8192 bf16
    float* part   = (float*)(wsb + 33554432);  // [16][512][384] fp32
    u16*   ao_all = (u16*)(wsb + 46137344);    // [8192][384]
    u16*   x1_all = (u16*)(wsb + 52428800);
    u16*   f0_all = (u16*)(wsb + 58720256);
    u16*   gl_all = (u16*)(wsb + 65011712);    // [8192][1536]
    u16*   qn     = (u16*)(wsb + 90177536);
    u16*   qb     = (u16*)(wsb + 90570752);
    float* den    = (float*)(wsb + 90963968);  // [16][512]
    u16*   w1T    = (u16*)(wsb + 90996736);
    u16*   w2T    = (u16*)(wsb + 91291648);
    u16*   w3T    = (u16*)(wsb + 91586560);
    u16*   wqT    = (u16*)(wsb + 91881472);
    u16*   wkvT   = (u16*)(wsb + 92176384);    // [768][384]; +147456 = wvT
    u16*   woT    = (u16*)(wsb + 92766208);
    u16*   ffw1T  = (u16*)(wsb + 93061120);    // [3072][384]
    u16*   ffw2T  = (u16*)(wsb + 95420416);    // [384][1536] -> end 96600064

    const int FULLMASK = 0x3FFFFFFF;

    // ---- setup: weight conversions + den zero + q path ----
    wconv_kernel<<<576,  256, 0, stream>>>(w1,   w1T,   384, 384);
    wconv_kernel<<<576,  256, 0, stream>>>(w2,   w2T,   384, 384);
    wconv_kernel<<<576,  256, 0, stream>>>(w3,   w3T,   384, 384);
    wconv_kernel<<<576,  256, 0, stream>>>(wq,   wqT,   384, 384);
    wconv_kernel<<<1152, 256, 0, stream>>>(wkv,  wkvT,  384, 768);
    wconv_kernel<<<576,  256, 0, stream>>>(wo,   woT,   384, 384);
    wconv_kernel<<<4608, 256, 0, stream>>>(ffw1, ffw1T, 384, 3072);
    wconv_kernel<<<2304, 256, 0, stream>>>(ffw2, ffw2T, 1536, 384);
    hipMemsetAsync(den, 0, 16 * 512 * sizeof(float), stream);
    ln_kernel<1><<<128, 256, 0, stream>>>(query, lnqg, lnqb, qn, 512);
    gemm_mfma<0, 0><<<dim3(4, 6), 256, 0, stream>>>(qn, wqT, nullptr, nullptr, qb,
        512, 384, 384, 384, 384, 384, 0, 1.f, 0, FULLMASK);

    // ---- phase 1: per batch ----
    for (int b = 0; b < 16; ++b) {
        const float* xb = x + (long long)b * 24576;

        layer0_kernel<<<3072, 256, 0, stream>>>(xb, w0, b0, hA, 786432);
        gemm_mfma<0, 0><<<dim3(64, 6), 256, 0, stream>>>(hA, w1T, b1, nullptr, hB,
            8192, 384, 384, 384, 384, 384, 0, 1.f, 1, FULLMASK);
        gemm_mfma<0, 0><<<dim3(64, 6), 256, 0, stream>>>(hB, w2T, b2, nullptr, hA,
            8192, 384, 384, 384, 384, 384, 0, 1.f, 1, FULLMASK);
        gemm_mfma<0, 0><<<dim3(64, 6), 256, 0, stream>>>(hA, w3T, b3, nullptr, hB,
            8192, 384, 384, 384, 384, 384, 0, 1.f, 0, FULLMASK);   // ctx -> hB
        ln_kernel<0><<<2048, 256, 0, stream>>>(hB, lncg, lncb, hA, 8192); // kn -> hA
        // K = kn @ wk   [8192][384]
        gemm_mfma<0, 0><<<dim3(64, 6), 256, 0, stream>>>(hA, wkvT, nullptr, nullptr, Kb,
            8192, 384, 384, 384, 384, 384, 0, 1.f, 0, FULLMASK);
        // VT = wv^T @ kn^T   [384][8192]
        gemm_mfma<0, 0><<<dim3(3, 128), 256, 0, stream>>>(wkvT + 147456, hA,
            nullptr, nullptr, VTb, 384, 8192, 384, 384, 384, 8192, 0, 1.f, 0, FULLMASK);
        // P = exp(scale * q @ K^T), den[b] += row sums
        gemm_exp<<<dim3(4, 128), 256, 0, stream>>>(qb, Kb, Pb, den + b * 512,
            384, 384, 384, 8192, 0.05103103630798288f);
        // PV split-K partials
        gemm_pv<<<dim3(4, 6, 16), 256, 0, stream>>>(Pb, VTb, part, 8192, 8192);
        // reduce -> ao_all[b]
        pv_reduce_kernel<<<192, 256, 0, stream>>>(part, den + b * 512,
            ao_all + (long long)b * 196608);
    }

    // ---- phase 2: batched across all 16 ----
    // x1 = ao @ wo + bo + query (query broadcast rows via m & 511)
    gemm_mfma<1, 0><<<dim3(64, 6), 256, 0, stream>>>(ao_all, woT, bo, query, x1_all,
        8192, 384, 384, 384, 384, 384, 384, 1.f, 0, 511);
    ln_kernel<0><<<2048, 256, 0, stream>>>(x1_all, lnfg, lnfb, f0_all, 8192);
    // gl = geglu(f0 @ ffw1 + ffb1)
    gemm_ff1_geglu<<<dim3(64, 24), 256, 0, stream>>>(f0_all, ffw1T, ffb1, gl_all,
        384, 384, 384, 1536);
    // out (fp32) = gl @ ffw2 + ffb2 + x1
    gemm_mfma<0, 1><<<dim3(64, 6), 256, 0, stream>>>(gl_all, ffw2T, ffb2, x1_all, out,
        8192, 384, 1536, 1536, 1536, 384, 384, 1.f, 0, FULLMASK);
}

// Round 12
// 1127.939 us; speedup vs baseline: 8.7552x; 1.7220x over previous
//
#include <hip/hip_runtime.h>
#include <math.h>

// B=16, N=8192, L=512, D=384, FF=1536. INPUTS fp32, OUTPUT fp32.
// MFMA bf16 GEMMs; phase 1 processes G batches at once (G chosen from ws_size:
// need(2)=92MB <= 96.6MB proven; 4->147MB, 8->256MB, 16->474MB used only if
// the harness provides them). Phase 2 batched across all 16.

typedef unsigned short u16;
typedef unsigned int   u32;
typedef __bf16 bf16_t;
typedef bf16_t bf16x8 __attribute__((ext_vector_type(8)));
typedef float  floatx4 __attribute__((ext_vector_type(4)));

__device__ __forceinline__ float b2f(u16 v) {
    return __uint_as_float(((u32)v) << 16);
}
__device__ __forceinline__ u16 f2b(float f) {
    u32 u = __float_as_uint(f);
    return (u16)((u + 0x7FFFu + ((u >> 16) & 1u)) >> 16);   // RNE
}
__device__ __forceinline__ void stb4(u16* p, float4 f) {
    uint2 v;
    v.x = (u32)f2b(f.x) | ((u32)f2b(f.y) << 16);
    v.y = (u32)f2b(f.z) | ((u32)f2b(f.w) << 16);
    *(uint2*)p = v;
}

// ---------------------------------------------------------------------------
// Weight convert: W fp32 [Kd][Nd] -> WT bf16 [Nd][Kd]
__global__ __launch_bounds__(256) void wconv_kernel(
    const float* __restrict__ W, u16* __restrict__ WT, int Kd, int Nd)
{
    int idx = blockIdx.x * 256 + threadIdx.x;
    if (idx >= Kd * Nd) return;
    int n = idx / Kd, k = idx - n * Kd;
    WT[idx] = f2b(W[(long long)k * Nd + n]);
}

// ---------------------------------------------------------------------------
// Layer 0: h = relu(x @ w0 + b0); x fp32 [M][3], out bf16
__global__ __launch_bounds__(256) void layer0_kernel(
    const float* __restrict__ X, const float* __restrict__ W0,
    const float* __restrict__ B0, u16* __restrict__ H, int total4)
{
    int idx = blockIdx.x * 256 + threadIdx.x;
    if (idx >= total4) return;
    int e = idx * 4;
    int m = e / 384;
    int j = e - m * 384;
    float x0 = X[m * 3 + 0], x1 = X[m * 3 + 1], x2 = X[m * 3 + 2];
    float4 w0 = *(const float4*)(W0 + j);
    float4 w1 = *(const float4*)(W0 + 384 + j);
    float4 w2 = *(const float4*)(W0 + 768 + j);
    float4 bb = *(const float4*)(B0 + j);
    float4 v;
    v.x = fmaxf(bb.x + x0 * w0.x + x1 * w1.x + x2 * w2.x, 0.f);
    v.y = fmaxf(bb.y + x0 * w0.y + x1 * w1.y + x2 * w2.y, 0.f);
    v.z = fmaxf(bb.z + x0 * w0.z + x1 * w1.z + x2 * w2.z, 0.f);
    v.w = fmaxf(bb.w + x0 * w0.w + x1 * w1.w + x2 * w2.w, 0.f);
    stb4(H + e, v);
}

// ---------------------------------------------------------------------------
// LayerNorm; input fp32 (IN_F32=1) or bf16; g,b fp32; out bf16. 4 rows/block.
template<int IN_F32>
__global__ __launch_bounds__(256) void ln_kernel(
    const void* __restrict__ Xv, const float* __restrict__ g,
    const float* __restrict__ b, u16* __restrict__ Y, int rows)
{
    int w = threadIdx.x >> 6, lane = threadIdx.x & 63;
    int row = blockIdx.x * 4 + w;
    if (row >= rows) return;
    float v[6];
    float s = 0.f, ss = 0.f;
#pragma unroll
    for (int i = 0; i < 6; ++i) {
        int c = i * 64 + lane;
        v[i] = IN_F32 ? ((const float*)Xv)[(long long)row * 384 + c]
                      : b2f(((const u16*)Xv)[(long long)row * 384 + c]);
        s += v[i]; ss += v[i] * v[i];
    }
#pragma unroll
    for (int m = 32; m; m >>= 1) {
        s  += __shfl_xor(s, m, 64);
        ss += __shfl_xor(ss, m, 64);
    }
    float mean = s * (1.0f / 384.0f);
    float var  = ss * (1.0f / 384.0f) - mean * mean;
    float rs = rsqrtf(fmaxf(var, 0.f) + 1e-5f);
    u16* yr = Y + (long long)row * 384;
#pragma unroll
    for (int i = 0; i < 6; ++i) {
        int c = i * 64 + lane;
        yr[c] = f2b((v[i] - mean) * rs * g[c] + b[c]);
    }
}

// ---------------------------------------------------------------------------
// MFMA core macro for the 128x64x32 tile (4 waves). Verified C/D layout.
#define MFMA_TILE_LOOP(Aptr, Bptr, LDA, LDB, K0, K1)                          \
    for (int k0 = (K0); k0 < (K1); k0 += 32) {                                \
        __syncthreads();                                                      \
        _Pragma("unroll")                                                     \
        for (int s = 0; s < 2; ++s) {                                         \
            int slot = tid + s * 256;                                         \
            int r = slot >> 2, sg = slot & 3;                                 \
            *(uint4*)&As[r][sg * 8] =                                         \
                *(const uint4*)((Aptr) + (long long)(m0 + r) * (LDA) + k0 + sg * 8); \
        }                                                                     \
        {                                                                     \
            int r = tid >> 2, sg = tid & 3;                                   \
            *(uint4*)&Bs[r][sg * 8] =                                         \
                *(const uint4*)((Bptr) + (long long)(n0 + r) * (LDB) + k0 + sg * 8); \
        }                                                                     \
        __syncthreads();                                                      \
        bf16x8 a0 = *(const bf16x8*)&As[wv * 32 + lr][lq * 8];                \
        bf16x8 a1 = *(const bf16x8*)&As[wv * 32 + 16 + lr][lq * 8];           \
        bf16x8 b0 = *(const bf16x8*)&Bs[lr][lq * 8];                          \
        bf16x8 b1 = *(const bf16x8*)&Bs[16 + lr][lq * 8];                     \
        bf16x8 b2 = *(const bf16x8*)&Bs[32 + lr][lq * 8];                     \
        bf16x8 b3 = *(const bf16x8*)&Bs[48 + lr][lq * 8];                     \
        acc[0][0] = __builtin_amdgcn_mfma_f32_16x16x32_bf16(a0, b0, acc[0][0], 0, 0, 0); \
        acc[0][1] = __builtin_amdgcn_mfma_f32_16x16x32_bf16(a0, b1, acc[0][1], 0, 0, 0); \
        acc[0][2] = __builtin_amdgcn_mfma_f32_16x16x32_bf16(a0, b2, acc[0][2], 0, 0, 0); \
        acc[0][3] = __builtin_amdgcn_mfma_f32_16x16x32_bf16(a0, b3, acc[0][3], 0, 0, 0); \
        acc[1][0] = __builtin_amdgcn_mfma_f32_16x16x32_bf16(a1, b0, acc[1][0], 0, 0, 0); \
        acc[1][1] = __builtin_amdgcn_mfma_f32_16x16x32_bf16(a1, b1, acc[1][1], 0, 0, 0); \
        acc[1][2] = __builtin_amdgcn_mfma_f32_16x16x32_bf16(a1, b2, acc[1][2], 0, 0, 0); \
        acc[1][3] = __builtin_amdgcn_mfma_f32_16x16x32_bf16(a1, b3, acc[1][3], 0, 0, 0); \
    }

// Generic GEMM with z-strides: C = act(scale*A@WT^T + bias) + res.
template<int RES_F32, int OUT_F32>
__global__ __launch_bounds__(256) void gemm_mfma(
    const u16* __restrict__ A, const u16* __restrict__ WT,
    const float* __restrict__ bias, const void* __restrict__ res,
    void* __restrict__ C,
    int M, int N, int K, int lda, int ldb, int ldc, int ldres,
    float scale, int relu, int resmask,
    long long zsA, long long zsB, long long zsC)
{
    __shared__ u16 As[128][56];
    __shared__ u16 Bs[64][56];
    const int tid = threadIdx.x;
    const int wv = tid >> 6, lane = tid & 63;
    const int lr = lane & 15, lq = lane >> 4;
    const int m0 = blockIdx.x * 128;
    const int n0 = blockIdx.y * 64;
    const u16* Az = A + blockIdx.z * zsA;
    const u16* Bz = WT + blockIdx.z * zsB;
    const long long czoff = blockIdx.z * zsC;

    floatx4 acc[2][4];
#pragma unroll
    for (int i = 0; i < 2; ++i)
#pragma unroll
        for (int j = 0; j < 4; ++j)
            acc[i][j] = (floatx4){0.f, 0.f, 0.f, 0.f};

    MFMA_TILE_LOOP(Az, Bz, lda, ldb, 0, K)

#pragma unroll
    for (int ms = 0; ms < 2; ++ms) {
#pragma unroll
        for (int ns = 0; ns < 4; ++ns) {
            int col = n0 + ns * 16 + lr;
            float bi = bias ? bias[col] : 0.f;
#pragma unroll
            for (int r = 0; r < 4; ++r) {
                int m = m0 + wv * 32 + ms * 16 + lq * 4 + r;
                float v = acc[ms][ns][r] * scale + bi;
                if (relu) v = fmaxf(v, 0.f);
                if (res) {
                    long long ro = (long long)(m & resmask) * ldres + col;
                    v += RES_F32 ? ((const float*)res)[ro]
                                 : b2f(((const u16*)res)[ro]);
                }
                long long co = czoff + (long long)m * ldc + col;
                if (OUT_F32) ((float*)C)[co] = v;
                else         ((u16*)C)[co] = f2b(v);
            }
        }
    }
}

// ---------------------------------------------------------------------------
// S-with-exp GEMM (z over group): P = exp(clamp(scale*q@K^T)), den += row sums.
__global__ __launch_bounds__(256) void gemm_exp(
    const u16* __restrict__ A, const u16* __restrict__ WT,
    u16* __restrict__ P, float* __restrict__ den,
    int K, int lda, int ldb, int ldc, float scale,
    long long zsB, long long zsP)
{
    __shared__ u16 As[128][56];
    __shared__ u16 Bs[64][56];
    const int tid = threadIdx.x;
    const int wv = tid >> 6, lane = tid & 63;
    const int lr = lane & 15, lq = lane >> 4;
    const int m0 = blockIdx.x * 128;
    const int n0 = blockIdx.y * 64;
    const u16* Bz = WT + blockIdx.z * zsB;
    u16* Pz = P + blockIdx.z * zsP;
    float* dz = den + blockIdx.z * 512;

    floatx4 acc[2][4];
#pragma unroll
    for (int i = 0; i < 2; ++i)
#pragma unroll
        for (int j = 0; j < 4; ++j)
            acc[i][j] = (floatx4){0.f, 0.f, 0.f, 0.f};

    MFMA_TILE_LOOP(A, Bz, lda, ldb, 0, K)

    float srow[2][4] = {};
#pragma unroll
    for (int ms = 0; ms < 2; ++ms) {
#pragma unroll
        for (int ns = 0; ns < 4; ++ns) {
            int col = n0 + ns * 16 + lr;
#pragma unroll
            for (int r = 0; r < 4; ++r) {
                int m = m0 + wv * 32 + ms * 16 + lq * 4 + r;
                float l = acc[ms][ns][r] * scale;
                l = fminf(fmaxf(l, -60.f), 60.f);
                float p = __expf(l);
                Pz[(long long)m * ldc + col] = f2b(p);
                srow[ms][r] += p;
            }
        }
    }
#pragma unroll
    for (int ms = 0; ms < 2; ++ms)
#pragma unroll
        for (int r = 0; r < 4; ++r) {
            float s = srow[ms][r];
            s += __shfl_xor(s, 1, 64);
            s += __shfl_xor(s, 2, 64);
            s += __shfl_xor(s, 4, 64);
            s += __shfl_xor(s, 8, 64);
            if (lr == 0)
                atomicAdd(&dz[m0 + wv * 32 + ms * 16 + lq * 4 + r], s);
        }
}

// ---------------------------------------------------------------------------
// Split-K PV over group: z = g*SPLIT + s; part[z] = P_g[:, ks..] @ VT_g[:, ks..]^T
__global__ __launch_bounds__(256) void gemm_pv(
    const u16* __restrict__ P, const u16* __restrict__ VT,
    float* __restrict__ part, int SPLIT)
{
    __shared__ u16 As[128][56];
    __shared__ u16 Bs[64][56];
    const int tid = threadIdx.x;
    const int wv = tid >> 6, lane = tid & 63;
    const int lr = lane & 15, lq = lane >> 4;
    const int m0 = blockIdx.x * 128;
    const int n0 = blockIdx.y * 64;
    const int z = blockIdx.z;
    const int g = z / SPLIT, sp = z - g * SPLIT;
    const int chunk = 8192 / SPLIT;
    const u16* Az = P + (long long)g * 512 * 8192;
    const u16* Bz = VT + (long long)g * 384 * 8192;

    floatx4 acc[2][4];
#pragma unroll
    for (int i = 0; i < 2; ++i)
#pragma unroll
        for (int j = 0; j < 4; ++j)
            acc[i][j] = (floatx4){0.f, 0.f, 0.f, 0.f};

    MFMA_TILE_LOOP(Az, Bz, 8192, 8192, sp * chunk, (sp + 1) * chunk)

    float* pz = part + (long long)z * 512 * 384;
#pragma unroll
    for (int ms = 0; ms < 2; ++ms)
#pragma unroll
        for (int ns = 0; ns < 4; ++ns) {
            int col = n0 + ns * 16 + lr;
#pragma unroll
            for (int r = 0; r < 4; ++r) {
                int m = m0 + wv * 32 + ms * 16 + lq * 4 + r;
                pz[(long long)m * 384 + col] = acc[ms][ns][r];
            }
        }
}

// ---------------------------------------------------------------------------
// PV reduce over group: ao[g][q][d] = (sum_s part[g*SPLIT+s][q][d]) / den[g*512+q]
__global__ __launch_bounds__(256) void pv_reduce_kernel(
    const float* __restrict__ part, const float* __restrict__ den,
    u16* __restrict__ AO, int SPLIT)
{
    int idx = blockIdx.x * 256 + threadIdx.x;   // G*512*96 threads
    int q = idx / 96, j = (idx - q * 96) * 4;   // q in [0, G*512)
    int g = q >> 9, ql = q & 511;
    float4 s = make_float4(0.f, 0.f, 0.f, 0.f);
    for (int sp = 0; sp < SPLIT; ++sp) {
        const float* pz = part + (((long long)(g * SPLIT + sp) * 512 + ql) * 384 + j);
        float4 v = *(const float4*)pz;
        s.x += v.x; s.y += v.y; s.z += v.z; s.w += v.w;
    }
    float inv = 1.0f / den[q];
    s.x *= inv; s.y *= inv; s.z *= inv; s.w *= inv;
    stb4(AO + (long long)q * 384 + j, s);
}

// ---------------------------------------------------------------------------
// FF1 + GEGLU fused: gl = a * gelu(g)
__global__ __launch_bounds__(256) void gemm_ff1_geglu(
    const u16* __restrict__ A, const u16* __restrict__ WT,
    const float* __restrict__ bias, u16* __restrict__ C,
    int K, int lda, int ldb, int ldc)
{
    __shared__ u16 As[128][56];
    __shared__ u16 Bs[128][56];
    const int tid = threadIdx.x;
    const int wv = tid >> 6, lane = tid & 63;
    const int lr = lane & 15, lq = lane >> 4;
    const int m0 = blockIdx.x * 128;
    const int n0 = blockIdx.y * 64;

    floatx4 accA[2][4], accG[2][4];
#pragma unroll
    for (int i = 0; i < 2; ++i)
#pragma unroll
        for (int j = 0; j < 4; ++j) {
            accA[i][j] = (floatx4){0.f, 0.f, 0.f, 0.f};
            accG[i][j] = (floatx4){0.f, 0.f, 0.f, 0.f};
        }

    for (int k0 = 0; k0 < K; k0 += 32) {
        __syncthreads();
#pragma unroll
        for (int s = 0; s < 2; ++s) {
            int slot = tid + s * 256;
            int r = slot >> 2, sg = slot & 3;
            *(uint4*)&As[r][sg * 8] =
                *(const uint4*)(A + (long long)(m0 + r) * lda + k0 + sg * 8);
        }
#pragma unroll
        for (int s = 0; s < 2; ++s) {
            int slot = tid + s * 256;
            int r = slot >> 2, sg = slot & 3;
            int wrow = (r < 64) ? (n0 + r) : (1536 + n0 + r - 64);
            *(uint4*)&Bs[r][sg * 8] =
                *(const uint4*)(WT + (long long)wrow * ldb + k0 + sg * 8);
        }
        __syncthreads();
        bf16x8 a0 = *(const bf16x8*)&As[wv * 32 + lr][lq * 8];
        bf16x8 a1 = *(const bf16x8*)&As[wv * 32 + 16 + lr][lq * 8];
#pragma unroll
        for (int ns = 0; ns < 4; ++ns) {
            bf16x8 bA = *(const bf16x8*)&Bs[ns * 16 + lr][lq * 8];
            bf16x8 bG = *(const bf16x8*)&Bs[64 + ns * 16 + lr][lq * 8];
            accA[0][ns] = __builtin_amdgcn_mfma_f32_16x16x32_bf16(a0, bA, accA[0][ns], 0, 0, 0);
            accA[1][ns] = __builtin_amdgcn_mfma_f32_16x16x32_bf16(a1, bA, accA[1][ns], 0, 0, 0);
            accG[0][ns] = __builtin_amdgcn_mfma_f32_16x16x32_bf16(a0, bG, accG[0][ns], 0, 0, 0);
            accG[1][ns] = __builtin_amdgcn_mfma_f32_16x16x32_bf16(a1, bG, accG[1][ns], 0, 0, 0);
        }
    }

#pragma unroll
    for (int ms = 0; ms < 2; ++ms)
#pragma unroll
        for (int ns = 0; ns < 4; ++ns) {
            int col = n0 + ns * 16 + lr;
            float ba = bias[col];
            float bg = bias[1536 + col];
#pragma unroll
            for (int r = 0; r < 4; ++r) {
                int m = m0 + wv * 32 + ms * 16 + lq * 4 + r;
                float a = accA[ms][ns][r] + ba;
                float g = accG[ms][ns][r] + bg;
                float v = a * 0.5f * g * (1.0f + erff(g * 0.70710678118654752f));
                C[(long long)m * ldc + col] = f2b(v);
            }
        }
}

// ---------------------------------------------------------------------------
extern "C" void kernel_launch(void* const* d_in, const int* in_sizes, int n_in,
                              void* d_out, int out_size, void* d_ws, size_t ws_size,
                              hipStream_t stream) {
    const float* x     = (const float*)d_in[0];
    const float* w0    = (const float*)d_in[1];
    const float* b0    = (const float*)d_in[2];
    const float* w1    = (const float*)d_in[3];
    const float* b1    = (const float*)d_in[4];
    const float* w2    = (const float*)d_in[5];
    const float* b2    = (const float*)d_in[6];
    const float* w3    = (const float*)d_in[7];
    const float* b3    = (const float*)d_in[8];
    const float* query = (const float*)d_in[9];
    const float* lnqg  = (const float*)d_in[10];
    const float* lnqb  = (const float*)d_in[11];
    const float* lncg  = (const float*)d_in[12];
    const float* lncb  = (const float*)d_in[13];
    const float* wq    = (const float*)d_in[14];
    const float* wkv   = (const float*)d_in[15];
    const float* wo    = (const float*)d_in[16];
    const float* bo    = (const float*)d_in[17];
    const float* lnfg  = (const float*)d_in[18];
    const float* lnfb  = (const float*)d_in[19];
    const float* ffw1  = (const float*)d_in[20];
    const float* ffb1  = (const float*)d_in[21];
    const float* ffw2  = (const float*)d_in[22];
    const float* ffb2  = (const float*)d_in[23];
    float* out = (float*)d_out;
    char* wsb = (char*)d_ws;

    // ---- group size selection from ws_size ----
    auto need = [](int G) -> size_t {
        return (size_t)G * (3LL * 6291456 + 8388608)    // bufA,bufB,VT,P
             + 25165824                                 // part (32 slots)
             + 6291456                                  // ao_all
             + 2 * 393216 + 32768                       // qn, qb, den
             + 5603328;                                 // weight pool
    };
    int G = 2;
    if      (ws_size >= need(16)) G = 16;
    else if (ws_size >= need(8))  G = 8;
    else if (ws_size >= need(4))  G = 4;
    const int SPLIT = 32 / G;

    long long off = 0;
    u16*   bufA   = (u16*)(wsb + off); off += (long long)G * 6291456;
    u16*   bufB   = (u16*)(wsb + off); off += (long long)G * 6291456;
    u16*   VTb    = (u16*)(wsb + off); off += (long long)G * 6291456;
    u16*   Pb     = (u16*)(wsb + off); off += (long long)G * 8388608;
    float* part   = (float*)(wsb + off); off += 25165824;
    u16*   ao_all = (u16*)(wsb + off); off += 6291456;
    u16*   qn     = (u16*)(wsb + off); off += 393216;
    u16*   qb     = (u16*)(wsb + off); off += 393216;
    float* den    = (float*)(wsb + off); off += 32768;
    u16*   w1T    = (u16*)(wsb + off); off += 294912;
    u16*   w2T    = (u16*)(wsb + off); off += 294912;
    u16*   w3T    = (u16*)(wsb + off); off += 294912;
    u16*   wqT    = (u16*)(wsb + off); off += 294912;
    u16*   wkvT   = (u16*)(wsb + off); off += 589824;   // +147456 elems = wvT
    u16*   woT    = (u16*)(wsb + off); off += 294912;
    u16*   ffw1T  = (u16*)(wsb + off); off += 2359296;
    u16*   ffw2T  = (u16*)(wsb + off); off += 1179648;
    // phase-2 overlays (bufA/bufB/VT region is dead by then; >= 37.75MB for G>=2)
    u16*   x1_all = (u16*)(wsb + 0);
    u16*   f0_all = (u16*)(wsb + 6291456);
    u16*   gl_all = (u16*)(wsb + 12582912);   // 25.2MB, ends at 37748736

    const int FULLMASK = 0x3FFFFFFF;

    // ---- setup ----
    wconv_kernel<<<576,  256, 0, stream>>>(w1,   w1T,   384, 384);
    wconv_kernel<<<576,  256, 0, stream>>>(w2,   w2T,   384, 384);
    wconv_kernel<<<576,  256, 0, stream>>>(w3,   w3T,   384, 384);
    wconv_kernel<<<576,  256, 0, stream>>>(wq,   wqT,   384, 384);
    wconv_kernel<<<1152, 256, 0, stream>>>(wkv,  wkvT,  384, 768);
    wconv_kernel<<<576,  256, 0, stream>>>(wo,   woT,   384, 384);
    wconv_kernel<<<4608, 256, 0, stream>>>(ffw1, ffw1T, 384, 3072);
    wconv_kernel<<<2304, 256, 0, stream>>>(ffw2, ffw2T, 1536, 384);
    hipMemsetAsync(den, 0, 16 * 512 * sizeof(float), stream);
    ln_kernel<1><<<128, 256, 0, stream>>>(query, lnqg, lnqb, qn, 512);
    gemm_mfma<0, 0><<<dim3(4, 6), 256, 0, stream>>>(qn, wqT, nullptr, nullptr, qb,
        512, 384, 384, 384, 384, 384, 0, 1.f, 0, FULLMASK, 0, 0, 0);

    // ---- phase 1: groups of G batches ----
    const int MG = G * 8192;
    for (int base = 0; base < 16; base += G) {
        const float* xg = x + (long long)base * 24576;

        layer0_kernel<<<(MG * 96) / 256 / 256 * 256 ? (G * 3072) : (G * 3072), 256, 0, stream>>>(
            xg, w0, b0, bufA, G * 786432);
        gemm_mfma<0, 0><<<dim3(MG / 128, 6), 256, 0, stream>>>(bufA, w1T, b1, nullptr, bufB,
            MG, 384, 384, 384, 384, 384, 0, 1.f, 1, FULLMASK, 0, 0, 0);
        gemm_mfma<0, 0><<<dim3(MG / 128, 6), 256, 0, stream>>>(bufB, w2T, b2, nullptr, bufA,
            MG, 384, 384, 384, 384, 384, 0, 1.f, 1, FULLMASK, 0, 0, 0);
        gemm_mfma<0, 0><<<dim3(MG / 128, 6), 256, 0, stream>>>(bufA, w3T, b3, nullptr, bufB,
            MG, 384, 384, 384, 384, 384, 0, 1.f, 0, FULLMASK, 0, 0, 0);   // ctx -> bufB
        ln_kernel<0><<<MG / 4, 256, 0, stream>>>(bufB, lncg, lncb, bufA, MG);  // kn -> bufA
        // K_all = kn @ wk -> bufB
        gemm_mfma<0, 0><<<dim3(MG / 128, 6), 256, 0, stream>>>(bufA, wkvT, nullptr, nullptr, bufB,
            MG, 384, 384, 384, 384, 384, 0, 1.f, 0, FULLMASK, 0, 0, 0);
        // VT_g = wv^T @ kn_g^T  (z over group)
        gemm_mfma<0, 0><<<dim3(3, 128, G), 256, 0, stream>>>(wkvT + 147456, bufA,
            nullptr, nullptr, VTb, 384, 8192, 384, 384, 384, 8192, 0, 1.f, 0, FULLMASK,
            0, 8192LL * 384, 384LL * 8192);
        // P_g = exp(scale * q @ K_g^T), den += row sums
        gemm_exp<<<dim3(4, 128, G), 256, 0, stream>>>(qb, bufB, Pb, den + base * 512,
            384, 384, 384, 8192, 0.05103103630798288f, 8192LL * 384, 512LL * 8192);
        // PV split-K partials (z = g*SPLIT + s, 32 total)
        gemm_pv<<<dim3(4, 6, 32), 256, 0, stream>>>(Pb, VTb, part, SPLIT);
        // reduce -> ao_all[base..base+G)
        pv_reduce_kernel<<<G * 192, 256, 0, stream>>>(part, den + base * 512,
            ao_all + (long long)base * 196608, SPLIT);
    }

    // ---- phase 2: batched across all 16 ----
    gemm_mfma<1, 0><<<dim3(64, 6), 256, 0, stream>>>(ao_all, woT, bo, query, x1_all,
        8192, 384, 384, 384, 384, 384, 384, 1.f, 0, 511, 0, 0, 0);
    ln_kernel<0><<<2048, 256, 0, stream>>>(x1_all, lnfg, lnfb, f0_all, 8192);
    gemm_ff1_geglu<<<dim3(64, 24), 256, 0, stream>>>(f0_all, ffw1T, ffb1, gl_all,
        384, 384, 384, 1536);
    gemm_mfma<0, 1><<<dim3(64, 6), 256, 0, stream>>>(gl_all, ffw2T, ffb2, x1_all, out,
        8192, 384, 1536, 1536, 1536, 384, 384, 1.f, 0, FULLMASK, 0, 0, 0);
}